// Round 2
// baseline (11576.402 us; speedup 1.0000x reference)
//
#include <hip/hip_runtime.h>

#define FIN   128
#define HIDN  256
#define CDIM  40
#define NITER 40
#define RB    2048   // grid for grid-stride CG kernels / partial arrays
#define SB    512    // grid for stats partials

// ---------------- helpers ----------------

__device__ __forceinline__ float block_reduce_256(float v, float* red) {
  const int t = threadIdx.x;
  __syncthreads();           // protect reuse of red across calls
  red[t] = v;
  __syncthreads();
#pragma unroll
  for (int o = 128; o > 0; o >>= 1) {
    if (t < o) red[t] += red[t + o];
    __syncthreads();
  }
  return red[0];             // deterministic sum, visible to all threads
}

// ---------------- CSR build ----------------

__global__ void zero_i32(int* __restrict__ a, int n) {
  int i = blockIdx.x * blockDim.x + threadIdx.x;
  int s = gridDim.x * blockDim.x;
  for (; i < n; i += s) a[i] = 0;
}

__global__ void hist_kernel(const int* __restrict__ recv, int* __restrict__ cnt, int n) {
  int i = blockIdx.x * blockDim.x + threadIdx.x;
  int s = gridDim.x * blockDim.x;
  for (; i < n; i += s) atomicAdd(&cnt[recv[i]], 1);
}

__global__ __launch_bounds__(1024) void scan_kernel(const int* __restrict__ cnt,
                                                    int* __restrict__ rowp, int n) {
  __shared__ int sums[1024];
  const int t = threadIdx.x;
  const int chunk = (n + 1023) >> 10;
  const int lo = t * chunk;
  const int hi = min(lo + chunk, n);
  int s = 0;
  for (int i = lo; i < hi; ++i) s += cnt[i];
  sums[t] = s;
  __syncthreads();
  for (int o = 1; o < 1024; o <<= 1) {
    int v = (t >= o) ? sums[t - o] : 0;
    __syncthreads();
    sums[t] += v;
    __syncthreads();
  }
  int pre = (t == 0) ? 0 : sums[t - 1];
  for (int i = lo; i < hi; ++i) { rowp[i] = pre; pre += cnt[i]; }
  if (t == 0) rowp[n] = sums[1023];
}

__global__ void scatter_kernel(const int* __restrict__ send, const int* __restrict__ recv,
                               const float* __restrict__ ew, const int* __restrict__ rowp,
                               int* __restrict__ cur, int* __restrict__ cols,
                               float* __restrict__ wv, int n) {
  int i = blockIdx.x * blockDim.x + threadIdx.x;
  int s = gridDim.x * blockDim.x;
  for (; i < n; i += s) {
    int node = recv[i];
    int pos = atomicAdd(&cur[node], 1);
    int slot = rowp[node] + pos;
    cols[slot] = send[i];
    wv[slot] = ew[i];
  }
}

// ---------------- GEMM (f32, 128x64 tile, 8x4 per thread) ----------------
// C[M,Nn] = act(A)[M,K] @ W[K,Nn] + bias. If LNA: a' = relu(a*lnS[k]+lnT[k]).

template <bool LNA>
__global__ __launch_bounds__(256) void gemm_kernel(
    const float* __restrict__ A, const float* __restrict__ W,
    const float* __restrict__ bias, const float* __restrict__ lnS,
    const float* __restrict__ lnT, float* __restrict__ C, int M, int K, int Nn) {
  __shared__ float As[16][136];
  __shared__ float Bs[16][64];
  __shared__ float sS[256];
  __shared__ float sT[256];
  const int tid = threadIdx.x;
  if (LNA) {
    if (tid < K) { sS[tid] = lnS[tid]; sT[tid] = lnT[tid]; }
    __syncthreads();
  }
  const int tx = tid & 15, ty = tid >> 4;
  const int arow = tid >> 1, acol = (tid & 1) * 8;
  const int brow = tid >> 4, bcol = (tid & 15) * 4;
  const int rowBase = blockIdx.x * 128;
  const int colBase = blockIdx.y * 64;
  const int gr = rowBase + arow;
  float acc[8][4] = {};
  for (int k0 = 0; k0 < K; k0 += 16) {
    float av[8];
    if (gr < M) {
      const float4* ap = reinterpret_cast<const float4*>(A + (size_t)gr * K + k0 + acol);
      float4 v0 = ap[0];
      float4 v1 = ap[1];
      av[0] = v0.x; av[1] = v0.y; av[2] = v0.z; av[3] = v0.w;
      av[4] = v1.x; av[5] = v1.y; av[6] = v1.z; av[7] = v1.w;
    } else {
#pragma unroll
      for (int j = 0; j < 8; ++j) av[j] = 0.f;
    }
    if (LNA) {
#pragma unroll
      for (int j = 0; j < 8; ++j) {
        int k = k0 + acol + j;
        av[j] = fmaxf(fmaf(av[j], sS[k], sT[k]), 0.f);
      }
    }
    float bv[4];
    const int gk = k0 + brow;
#pragma unroll
    for (int j = 0; j < 4; ++j) {
      int gc = colBase + bcol + j;
      bv[j] = (gc < Nn) ? W[(size_t)gk * Nn + gc] : 0.f;
    }
    __syncthreads();
#pragma unroll
    for (int j = 0; j < 8; ++j) As[acol + j][arow] = av[j];
#pragma unroll
    for (int j = 0; j < 4; ++j) Bs[brow][bcol + j] = bv[j];
    __syncthreads();
#pragma unroll
    for (int kk = 0; kk < 16; ++kk) {
      float a[8], b[4];
#pragma unroll
      for (int i2 = 0; i2 < 8; ++i2) a[i2] = As[kk][ty * 8 + i2];
#pragma unroll
      for (int j = 0; j < 4; ++j) b[j] = Bs[kk][tx * 4 + j];
#pragma unroll
      for (int i2 = 0; i2 < 8; ++i2)
#pragma unroll
        for (int j = 0; j < 4; ++j)
          acc[i2][j] = fmaf(a[i2], b[j], acc[i2][j]);
    }
  }
#pragma unroll
  for (int i2 = 0; i2 < 8; ++i2) {
    int orow = rowBase + ty * 8 + i2;
    if (orow >= M) continue;
#pragma unroll
    for (int j = 0; j < 4; ++j) {
      int ocol = colBase + tx * 4 + j;
      if (ocol < Nn) C[(size_t)orow * Nn + ocol] = acc[i2][j] + bias[ocol];
    }
  }
}

// ---------------- in-place layer-1 GEMM ----------------
// Y <- relu(Y*lnS + lnT) @ W1 + b1, 128 rows per block, all 256 cols.
// Whole transformed A row-block staged in LDS (135 KB) => in-place is safe.

__global__ __launch_bounds__(256) void gemm1_inplace(
    float* __restrict__ Y, const float* __restrict__ W,
    const float* __restrict__ bias, const float* __restrict__ lnS,
    const float* __restrict__ lnT, int M) {
  __shared__ float As[HIDN][132];   // [k][row], 132*4B rows keep 16B alignment
  __shared__ float Bs[16][64];
  __shared__ float sS[HIDN];
  __shared__ float sT[HIDN];
  const int tid = threadIdx.x;
  sS[tid] = lnS[tid];
  sT[tid] = lnT[tid];
  __syncthreads();
  const int rowBase = blockIdx.x * 128;
  {
    const int r = tid >> 1;
    const int c0 = (tid & 1) * 128;
    const int gr = rowBase + r;
    if (gr < M) {
      const float4* src = reinterpret_cast<const float4*>(Y + (size_t)gr * HIDN + c0);
#pragma unroll
      for (int v4 = 0; v4 < 32; ++v4) {
        float4 vv = src[v4];
        int c = c0 + v4 * 4;
        As[c + 0][r] = fmaxf(fmaf(vv.x, sS[c + 0], sT[c + 0]), 0.f);
        As[c + 1][r] = fmaxf(fmaf(vv.y, sS[c + 1], sT[c + 1]), 0.f);
        As[c + 2][r] = fmaxf(fmaf(vv.z, sS[c + 2], sT[c + 2]), 0.f);
        As[c + 3][r] = fmaxf(fmaf(vv.w, sS[c + 3], sT[c + 3]), 0.f);
      }
    } else {
#pragma unroll
      for (int v4 = 0; v4 < 32; ++v4) {
        int c = c0 + v4 * 4;
        As[c + 0][r] = 0.f; As[c + 1][r] = 0.f;
        As[c + 2][r] = 0.f; As[c + 3][r] = 0.f;
      }
    }
  }
  const int tx = tid & 15, ty = tid >> 4;
  const int brow = tid >> 4, bcol = (tid & 15) * 4;
  for (int ct = 0; ct < 4; ++ct) {
    const int colBase = ct * 64;
    float acc[8][4] = {};
    for (int k0 = 0; k0 < HIDN; k0 += 16) {
      float bv[4];
#pragma unroll
      for (int j = 0; j < 4; ++j)
        bv[j] = W[(size_t)(k0 + brow) * HIDN + colBase + bcol + j];
      __syncthreads();   // first pass also orders the As writes above
#pragma unroll
      for (int j = 0; j < 4; ++j) Bs[brow][bcol + j] = bv[j];
      __syncthreads();
#pragma unroll
      for (int kk = 0; kk < 16; ++kk) {
        float a[8], b[4];
#pragma unroll
        for (int i2 = 0; i2 < 8; ++i2) a[i2] = As[k0 + kk][ty * 8 + i2];
#pragma unroll
        for (int j = 0; j < 4; ++j) b[j] = Bs[kk][tx * 4 + j];
#pragma unroll
        for (int i2 = 0; i2 < 8; ++i2)
#pragma unroll
          for (int j = 0; j < 4; ++j) acc[i2][j] = fmaf(a[i2], b[j], acc[i2][j]);
      }
    }
#pragma unroll
    for (int i2 = 0; i2 < 8; ++i2) {
      int orow = rowBase + ty * 8 + i2;
      if (orow >= M) continue;
#pragma unroll
      for (int j = 0; j < 4; ++j) {
        int oc = colBase + tx * 4 + j;
        Y[(size_t)orow * HIDN + oc] = acc[i2][j] + bias[oc];
      }
    }
  }
}

// ---------------- LayerNorm(axis=0) stats ----------------

__global__ __launch_bounds__(256) void stats_partial(const float* __restrict__ Y,
                                                     float* __restrict__ part, int M) {
  const int t = threadIdx.x;   // column
  float s = 0.f, s2 = 0.f;
  for (int row = blockIdx.x; row < M; row += SB) {
    float v = Y[(size_t)row * HIDN + t];
    s += v;
    s2 = fmaf(v, v, s2);
  }
  part[(size_t)blockIdx.x * 512 + t] = s;
  part[(size_t)blockIdx.x * 512 + 256 + t] = s2;
}

__global__ __launch_bounds__(256) void stats_final(const float* __restrict__ part,
                                                   const float* __restrict__ g,
                                                   const float* __restrict__ o,
                                                   float* __restrict__ lnS,
                                                   float* __restrict__ lnT, int M) {
  __shared__ float red[256];
  const int col = blockIdx.x;
  float s = 0.f, s2 = 0.f;
  for (int b = threadIdx.x; b < SB; b += 256) {
    s += part[(size_t)b * 512 + col];
    s2 += part[(size_t)b * 512 + 256 + col];
  }
  float ts = block_reduce_256(s, red);
  float ts2 = block_reduce_256(s2, red);
  if (threadIdx.x == 0) {
    float invM = 1.f / (float)M;
    float mean = ts * invM;
    float var = fmaxf(ts2 * invM - mean * mean, 0.f);
    float rstd = rsqrtf(var + 1e-5f);
    float sc = g[col] * rstd;
    lnS[col] = sc;
    lnT[col] = o[col] - mean * sc;
  }
}

// ---------------- CG ----------------
// b aliases x (both d_out): read b first, then zero x — same thread, safe.

__global__ __launch_bounds__(256) void cg_init(float* __restrict__ bx,
                                               float* __restrict__ r,
                                               float* __restrict__ p, float* __restrict__ rs_p,
                                               int total) {
  __shared__ float red[256];
  float rs = 0.f;
  for (int i = blockIdx.x * 256 + threadIdx.x; i < total; i += gridDim.x * 256) {
    float v = bx[i];
    r[i] = v;
    p[i] = v;
    bx[i] = 0.f;          // x = 0
    rs = fmaf(v, v, rs);
  }
  float s = block_reduce_256(rs, red);
  if (threadIdx.x == 0) rs_p[blockIdx.x] = s;
}

// q = (I - 0.9 S) p ; per-block partial of dot(p,q). One wave per node.
__global__ __launch_bounds__(256) void cg_matvec(const float* __restrict__ p,
                                                 float* __restrict__ q,
                                                 const int* __restrict__ rowp,
                                                 const int* __restrict__ cols,
                                                 const float* __restrict__ wv,
                                                 float* __restrict__ pqp, int N) {
  const int lane = threadIdx.x & 63;
  const int wid = threadIdx.x >> 6;
  const bool act = lane < CDIM;
  float pqacc = 0.f;
  for (int i = blockIdx.x * 4 + wid; i < N; i += gridDim.x * 4) {
    int beg = rowp[i], end = rowp[i + 1];
    float a0 = 0.f, a1 = 0.f, a2 = 0.f, a3 = 0.f;
    int e = beg;
    for (; e + 4 <= end; e += 4) {
      int c0 = cols[e], c1 = cols[e + 1], c2 = cols[e + 2], c3 = cols[e + 3];
      float w0 = wv[e], w1 = wv[e + 1], w2 = wv[e + 2], w3 = wv[e + 3];
      if (act) {
        a0 = fmaf(w0, p[(size_t)c0 * CDIM + lane], a0);
        a1 = fmaf(w1, p[(size_t)c1 * CDIM + lane], a1);
        a2 = fmaf(w2, p[(size_t)c2 * CDIM + lane], a2);
        a3 = fmaf(w3, p[(size_t)c3 * CDIM + lane], a3);
      }
    }
    for (; e < end; ++e) {
      int c = cols[e];
      float w = wv[e];
      if (act) a0 = fmaf(w, p[(size_t)c * CDIM + lane], a0);
    }
    if (act) {
      float pvv = p[(size_t)i * CDIM + lane];
      float qvv = fmaf(-0.9f, (a0 + a1) + (a2 + a3), pvv);
      q[(size_t)i * CDIM + lane] = qvv;
      pqacc = fmaf(pvv, qvv, pqacc);
    }
  }
#pragma unroll
  for (int o = 32; o > 0; o >>= 1) pqacc += __shfl_down(pqacc, o);
  __shared__ float wsum[4];
  if (lane == 0) wsum[wid] = pqacc;
  __syncthreads();
  if (threadIdx.x == 0) pqp[blockIdx.x] = (wsum[0] + wsum[1]) + (wsum[2] + wsum[3]);
}

__global__ __launch_bounds__(256) void cg_update(float* __restrict__ x, float* __restrict__ r,
                                                 const float* __restrict__ p,
                                                 const float* __restrict__ q,
                                                 const float* __restrict__ pqp,
                                                 const float* __restrict__ rsold_p,
                                                 float* __restrict__ rsnew_p, int total) {
  __shared__ float red[256];
  float s1 = 0.f, s2 = 0.f;
  for (int i = threadIdx.x; i < RB; i += 256) {
    s1 += pqp[i];
    s2 += rsold_p[i];
  }
  float pq = block_reduce_256(s1, red);
  float rsold = block_reduce_256(s2, red);
  float alpha = (pq > 0.f) ? (rsold / pq) : 0.f;
  float rs = 0.f;
  for (int i = blockIdx.x * 256 + threadIdx.x; i < total; i += gridDim.x * 256) {
    float pvv = p[i], qvv = q[i];
    x[i] = fmaf(alpha, pvv, x[i]);
    float rv2 = fmaf(-alpha, qvv, r[i]);
    r[i] = rv2;
    rs = fmaf(rv2, rv2, rs);
  }
  float bs = block_reduce_256(rs, red);
  if (threadIdx.x == 0) rsnew_p[blockIdx.x] = bs;
}

__global__ __launch_bounds__(256) void cg_axpy(float* __restrict__ p, const float* __restrict__ r,
                                               const float* __restrict__ rsold_p,
                                               const float* __restrict__ rsnew_p, int total) {
  __shared__ float red[256];
  float s1 = 0.f, s2 = 0.f;
  for (int i = threadIdx.x; i < RB; i += 256) {
    s1 += rsold_p[i];
    s2 += rsnew_p[i];
  }
  float rsold = block_reduce_256(s1, red);
  float rsnew = block_reduce_256(s2, red);
  float beta = (rsold > 0.f) ? (rsnew / rsold) : 0.f;
  for (int i = blockIdx.x * 256 + threadIdx.x; i < total; i += gridDim.x * 256) {
    p[i] = fmaf(beta, p[i], r[i]);
  }
}

// ---------------- launch ----------------

extern "C" void kernel_launch(void* const* d_in, const int* in_sizes, int n_in,
                              void* d_out, int out_size, void* d_ws, size_t ws_size,
                              hipStream_t stream) {
  const float* X   = (const float*)d_in[0];
  const int* send  = (const int*)d_in[1];
  const int* recv  = (const int*)d_in[2];
  const float* ew  = (const float*)d_in[3];
  const float* W0  = (const float*)d_in[4];
  const float* b0  = (const float*)d_in[5];
  const float* g0  = (const float*)d_in[6];
  const float* o0  = (const float*)d_in[7];
  const float* W1  = (const float*)d_in[8];
  const float* b1  = (const float*)d_in[9];
  const float* g1  = (const float*)d_in[10];
  const float* o1  = (const float*)d_in[11];
  const float* W2  = (const float*)d_in[12];
  const float* b2  = (const float*)d_in[13];

  const int N = in_sizes[0] / FIN;      // 169343
  const int E2 = in_sizes[1];           // 5418976
  const int total = N * CDIM;

  char* base = (char*)d_ws;
  size_t off = 0;
  auto carve = [&](size_t bytes) -> void* {
    void* ptr = base + off;
    off += (bytes + 255) & ~(size_t)255;
    return ptr;
  };
  int* cnt     = (int*)carve((size_t)N * 4);
  int* rowp    = (int*)carve((size_t)(N + 1) * 4);
  int* cols    = (int*)carve((size_t)E2 * 4);
  float* wv    = (float*)carve((size_t)E2 * 4);
  float* Y     = (float*)carve((size_t)N * HIDN * 4);  // reused for CG vectors
  float* statp = (float*)carve((size_t)SB * 512 * 4);
  float* lnS0  = (float*)carve(256 * 4);
  float* lnT0  = (float*)carve(256 * 4);
  float* lnS1  = (float*)carve(256 * 4);
  float* lnT1  = (float*)carve(256 * 4);
  float* pqp   = (float*)carve((size_t)RB * 4);
  float* rspA  = (float*)carve((size_t)RB * 4);
  float* rspB  = (float*)carve((size_t)RB * 4);
  (void)n_in; (void)out_size;

  // Diagnostic guard: if workspace is too small, do nothing (clean absmax
  // failure instead of an OOB crash).
  if (off > ws_size) return;

  // CG vectors overlay Y (dead after gemm2): 3*total < N*HIDN.
  float* rv = Y;
  float* pv = Y + (size_t)total;
  float* qv = Y + (size_t)2 * total;
  float* xv = (float*)d_out;   // also holds b right after gemm2

  // ---- CSR build (by receiver) ----
  zero_i32<<<RB, 256, 0, stream>>>(cnt, N);
  hist_kernel<<<RB, 256, 0, stream>>>(recv, cnt, E2);
  scan_kernel<<<1, 1024, 0, stream>>>(cnt, rowp, N);
  zero_i32<<<RB, 256, 0, stream>>>(cnt, N);
  scatter_kernel<<<RB, 256, 0, stream>>>(send, recv, ew, rowp, cnt, cols, wv, E2);

  // ---- MLP ----
  const int gm = (N + 127) / 128;
  gemm_kernel<false><<<dim3(gm, HIDN / 64), 256, 0, stream>>>(X, W0, b0, nullptr, nullptr,
                                                              Y, N, FIN, HIDN);
  stats_partial<<<SB, 256, 0, stream>>>(Y, statp, N);
  stats_final<<<HIDN, 256, 0, stream>>>(statp, g0, o0, lnS0, lnT0, N);
  gemm1_inplace<<<gm, 256, 0, stream>>>(Y, W1, b1, lnS0, lnT0, N);
  stats_partial<<<SB, 256, 0, stream>>>(Y, statp, N);
  stats_final<<<HIDN, 256, 0, stream>>>(statp, g1, o1, lnS1, lnT1, N);
  gemm_kernel<true><<<dim3(gm, 1), 256, 0, stream>>>(Y, W2, b2, lnS1, lnT1,
                                                     xv, N, HIDN, CDIM);

  // ---- CG: (I - 0.9 S) x = b, x0 = 0, fixed iteration count ----
  cg_init<<<RB, 256, 0, stream>>>(xv, rv, pv, rspA, total);
  for (int it = 0; it < NITER; ++it) {
    float* rs_old = (it & 1) ? rspB : rspA;
    float* rs_new = (it & 1) ? rspA : rspB;
    cg_matvec<<<RB, 256, 0, stream>>>(pv, qv, rowp, cols, wv, pqp, N);
    cg_update<<<RB, 256, 0, stream>>>(xv, rv, pv, qv, pqp, rs_old, rs_new, total);
    cg_axpy<<<RB, 256, 0, stream>>>(pv, rv, rs_old, rs_new, total);
  }
}

// Round 3
// 6390.425 us; speedup vs baseline: 1.8115x; 1.8115x over previous
//
#include <hip/hip_runtime.h>

#define FIN   128
#define HIDN  256
#define CDIM  40
#define NITER 20
#define RB    2048   // grid for grid-stride CG kernels / partial arrays
#define SB    512    // grid for stats partials

// ---------------- helpers ----------------

__device__ __forceinline__ float block_reduce_256(float v, float* red) {
  const int t = threadIdx.x;
  __syncthreads();           // protect reuse of red across calls
  red[t] = v;
  __syncthreads();
#pragma unroll
  for (int o = 128; o > 0; o >>= 1) {
    if (t < o) red[t] += red[t + o];
    __syncthreads();
  }
  return red[0];             // deterministic sum, visible to all threads
}

// ---------------- CSR build ----------------

__global__ void zero_i32(int* __restrict__ a, int n) {
  int i = blockIdx.x * blockDim.x + threadIdx.x;
  int s = gridDim.x * blockDim.x;
  for (; i < n; i += s) a[i] = 0;
}

__global__ void hist_kernel(const int* __restrict__ recv, int* __restrict__ cnt, int n) {
  int i = blockIdx.x * blockDim.x + threadIdx.x;
  int s = gridDim.x * blockDim.x;
  for (; i < n; i += s) atomicAdd(&cnt[recv[i]], 1);
}

__global__ __launch_bounds__(1024) void scan_kernel(const int* __restrict__ cnt,
                                                    int* __restrict__ rowp, int n) {
  __shared__ int sums[1024];
  const int t = threadIdx.x;
  const int chunk = (n + 1023) >> 10;
  const int lo = t * chunk;
  const int hi = min(lo + chunk, n);
  int s = 0;
  for (int i = lo; i < hi; ++i) s += cnt[i];
  sums[t] = s;
  __syncthreads();
  for (int o = 1; o < 1024; o <<= 1) {
    int v = (t >= o) ? sums[t - o] : 0;
    __syncthreads();
    sums[t] += v;
    __syncthreads();
  }
  int pre = (t == 0) ? 0 : sums[t - 1];
  for (int i = lo; i < hi; ++i) { rowp[i] = pre; pre += cnt[i]; }
  if (t == 0) rowp[n] = sums[1023];
}

__global__ void scatter_kernel(const int* __restrict__ send, const int* __restrict__ recv,
                               const float* __restrict__ ew, const int* __restrict__ rowp,
                               int* __restrict__ cur, int* __restrict__ cols,
                               float* __restrict__ wv, int n) {
  int i = blockIdx.x * blockDim.x + threadIdx.x;
  int s = gridDim.x * blockDim.x;
  for (; i < n; i += s) {
    int node = recv[i];
    int pos = atomicAdd(&cur[node], 1);
    int slot = rowp[node] + pos;
    cols[slot] = send[i];
    wv[slot] = ew[i];
  }
}

// ---------------- GEMM (f32, 128x64 tile, 8x4 per thread) ----------------
// C[M,Nn] = act(A)[M,K] @ W[K,Nn] + bias. If LNA: a' = relu(a*lnS[k]+lnT[k]).

template <bool LNA>
__global__ __launch_bounds__(256) void gemm_kernel(
    const float* __restrict__ A, const float* __restrict__ W,
    const float* __restrict__ bias, const float* __restrict__ lnS,
    const float* __restrict__ lnT, float* __restrict__ C, int M, int K, int Nn) {
  __shared__ float As[16][136];
  __shared__ float Bs[16][64];
  __shared__ float sS[256];
  __shared__ float sT[256];
  const int tid = threadIdx.x;
  if (LNA) {
    if (tid < K) { sS[tid] = lnS[tid]; sT[tid] = lnT[tid]; }
    __syncthreads();
  }
  const int tx = tid & 15, ty = tid >> 4;
  const int arow = tid >> 1, acol = (tid & 1) * 8;
  const int brow = tid >> 4, bcol = (tid & 15) * 4;
  const int rowBase = blockIdx.x * 128;
  const int colBase = blockIdx.y * 64;
  const int gr = rowBase + arow;
  float acc[8][4] = {};
  for (int k0 = 0; k0 < K; k0 += 16) {
    float av[8];
    if (gr < M) {
      const float4* ap = reinterpret_cast<const float4*>(A + (size_t)gr * K + k0 + acol);
      float4 v0 = ap[0];
      float4 v1 = ap[1];
      av[0] = v0.x; av[1] = v0.y; av[2] = v0.z; av[3] = v0.w;
      av[4] = v1.x; av[5] = v1.y; av[6] = v1.z; av[7] = v1.w;
    } else {
#pragma unroll
      for (int j = 0; j < 8; ++j) av[j] = 0.f;
    }
    if (LNA) {
#pragma unroll
      for (int j = 0; j < 8; ++j) {
        int k = k0 + acol + j;
        av[j] = fmaxf(fmaf(av[j], sS[k], sT[k]), 0.f);
      }
    }
    float bv[4];
    const int gk = k0 + brow;
#pragma unroll
    for (int j = 0; j < 4; ++j) {
      int gc = colBase + bcol + j;
      bv[j] = (gc < Nn) ? W[(size_t)gk * Nn + gc] : 0.f;
    }
    __syncthreads();
#pragma unroll
    for (int j = 0; j < 8; ++j) As[acol + j][arow] = av[j];
#pragma unroll
    for (int j = 0; j < 4; ++j) Bs[brow][bcol + j] = bv[j];
    __syncthreads();
#pragma unroll
    for (int kk = 0; kk < 16; ++kk) {
      float a[8], b[4];
#pragma unroll
      for (int i2 = 0; i2 < 8; ++i2) a[i2] = As[kk][ty * 8 + i2];
#pragma unroll
      for (int j = 0; j < 4; ++j) b[j] = Bs[kk][tx * 4 + j];
#pragma unroll
      for (int i2 = 0; i2 < 8; ++i2)
#pragma unroll
        for (int j = 0; j < 4; ++j)
          acc[i2][j] = fmaf(a[i2], b[j], acc[i2][j]);
    }
  }
#pragma unroll
  for (int i2 = 0; i2 < 8; ++i2) {
    int orow = rowBase + ty * 8 + i2;
    if (orow >= M) continue;
#pragma unroll
    for (int j = 0; j < 4; ++j) {
      int ocol = colBase + tx * 4 + j;
      if (ocol < Nn) C[(size_t)orow * Nn + ocol] = acc[i2][j] + bias[ocol];
    }
  }
}

// ---------------- in-place layer-1 GEMM ----------------
// Y <- relu(Y*lnS + lnT) @ W1 + b1. 128 rows/block, K staged in two
// 128-wide halves (LDS ~74 KB -> 2 blocks/CU). All reads of the block's
// rows complete before any write (acc held across both halves).

__global__ __launch_bounds__(256, 2) void gemm1_inplace(
    float* __restrict__ Y, const float* __restrict__ W,
    const float* __restrict__ bias, const float* __restrict__ lnS,
    const float* __restrict__ lnT, int M) {
  __shared__ float As[128][132];   // [k-within-half][row]
  __shared__ float Bs[16][64];
  __shared__ float sS[HIDN];
  __shared__ float sT[HIDN];
  const int tid = threadIdx.x;
  sS[tid] = lnS[tid];
  sT[tid] = lnT[tid];
  const int rowBase = blockIdx.x * 128;
  const int r = tid >> 1;            // 0..127
  const int c0 = (tid & 1) * 64;     // 0 or 64 within the 128-wide half
  const int gr = rowBase + r;
  const int tx = tid & 15, ty = tid >> 4;
  const int brow = tid >> 4, bcol = (tid & 15) * 4;
  float acc[4][8][4] = {};
#pragma unroll
  for (int kh = 0; kh < 2; ++kh) {
    __syncthreads();   // kh=0: orders sS/sT writes; kh=1: protects As readers
    if (gr < M) {
      const float4* src =
          reinterpret_cast<const float4*>(Y + (size_t)gr * HIDN + kh * 128 + c0);
#pragma unroll
      for (int v4 = 0; v4 < 16; ++v4) {
        float4 vv = src[v4];
        int cl = c0 + v4 * 4;
        int cg = kh * 128 + cl;
        As[cl + 0][r] = fmaxf(fmaf(vv.x, sS[cg + 0], sT[cg + 0]), 0.f);
        As[cl + 1][r] = fmaxf(fmaf(vv.y, sS[cg + 1], sT[cg + 1]), 0.f);
        As[cl + 2][r] = fmaxf(fmaf(vv.z, sS[cg + 2], sT[cg + 2]), 0.f);
        As[cl + 3][r] = fmaxf(fmaf(vv.w, sS[cg + 3], sT[cg + 3]), 0.f);
      }
    } else {
#pragma unroll
      for (int v4 = 0; v4 < 16; ++v4) {
        int cl = c0 + v4 * 4;
        As[cl + 0][r] = 0.f; As[cl + 1][r] = 0.f;
        As[cl + 2][r] = 0.f; As[cl + 3][r] = 0.f;
      }
    }
    __syncthreads();
#pragma unroll
    for (int ct = 0; ct < 4; ++ct) {
      const int colBase = ct * 64;
      for (int k0 = 0; k0 < 128; k0 += 16) {
        float bv[4];
#pragma unroll
        for (int j = 0; j < 4; ++j)
          bv[j] = W[(size_t)(kh * 128 + k0 + brow) * HIDN + colBase + bcol + j];
        __syncthreads();   // protect Bs from previous step's readers
#pragma unroll
        for (int j = 0; j < 4; ++j) Bs[brow][bcol + j] = bv[j];
        __syncthreads();
#pragma unroll
        for (int kk = 0; kk < 16; ++kk) {
          float a[8], b[4];
#pragma unroll
          for (int i2 = 0; i2 < 8; ++i2) a[i2] = As[k0 + kk][ty * 8 + i2];
#pragma unroll
          for (int j = 0; j < 4; ++j) b[j] = Bs[kk][tx * 4 + j];
#pragma unroll
          for (int i2 = 0; i2 < 8; ++i2)
#pragma unroll
            for (int j = 0; j < 4; ++j)
              acc[ct][i2][j] = fmaf(a[i2], b[j], acc[ct][i2][j]);
        }
      }
    }
  }
#pragma unroll
  for (int ct = 0; ct < 4; ++ct) {
#pragma unroll
    for (int i2 = 0; i2 < 8; ++i2) {
      int orow = rowBase + ty * 8 + i2;
      if (orow >= M) continue;
#pragma unroll
      for (int j = 0; j < 4; ++j) {
        int oc = ct * 64 + tx * 4 + j;
        Y[(size_t)orow * HIDN + oc] = acc[ct][i2][j] + bias[oc];
      }
    }
  }
}

// ---------------- LayerNorm(axis=0) stats ----------------

__global__ __launch_bounds__(256) void stats_partial(const float* __restrict__ Y,
                                                     float* __restrict__ part, int M) {
  const int t = threadIdx.x;   // column
  float s = 0.f, s2 = 0.f;
  for (int row = blockIdx.x; row < M; row += SB) {
    float v = Y[(size_t)row * HIDN + t];
    s += v;
    s2 = fmaf(v, v, s2);
  }
  part[(size_t)blockIdx.x * 512 + t] = s;
  part[(size_t)blockIdx.x * 512 + 256 + t] = s2;
}

__global__ __launch_bounds__(256) void stats_final(const float* __restrict__ part,
                                                   const float* __restrict__ g,
                                                   const float* __restrict__ o,
                                                   float* __restrict__ lnS,
                                                   float* __restrict__ lnT, int M) {
  __shared__ float red[256];
  const int col = blockIdx.x;
  float s = 0.f, s2 = 0.f;
  for (int b = threadIdx.x; b < SB; b += 256) {
    s += part[(size_t)b * 512 + col];
    s2 += part[(size_t)b * 512 + 256 + col];
  }
  float ts = block_reduce_256(s, red);
  float ts2 = block_reduce_256(s2, red);
  if (threadIdx.x == 0) {
    float invM = 1.f / (float)M;
    float mean = ts * invM;
    float var = fmaxf(ts2 * invM - mean * mean, 0.f);
    float rstd = rsqrtf(var + 1e-5f);
    float sc = g[col] * rstd;
    lnS[col] = sc;
    lnT[col] = o[col] - mean * sc;
  }
}

// ---------------- CG ----------------
// b aliases x (both d_out): read b first, then zero x — same thread, safe.

__global__ __launch_bounds__(256) void cg_init(float* __restrict__ bx,
                                               float* __restrict__ r,
                                               float* __restrict__ p, float* __restrict__ rs_p,
                                               int total) {
  __shared__ float red[256];
  float rs = 0.f;
  for (int i = blockIdx.x * 256 + threadIdx.x; i < total; i += gridDim.x * 256) {
    float v = bx[i];
    r[i] = v;
    p[i] = v;
    bx[i] = 0.f;          // x = 0
    rs = fmaf(v, v, rs);
  }
  float s = block_reduce_256(rs, red);
  if (threadIdx.x == 0) rs_p[blockIdx.x] = s;
}

// q = (I - 0.9 S) p ; per-block partial of dot(p,q). One wave per node,
// 8-deep edge unroll for gather-latency hiding.
__global__ __launch_bounds__(256) void cg_matvec(const float* __restrict__ p,
                                                 float* __restrict__ q,
                                                 const int* __restrict__ rowp,
                                                 const int* __restrict__ cols,
                                                 const float* __restrict__ wv,
                                                 float* __restrict__ pqp, int N) {
  const int lane = threadIdx.x & 63;
  const int wid = threadIdx.x >> 6;
  const bool act = lane < CDIM;
  float pqacc = 0.f;
  for (int i = blockIdx.x * 4 + wid; i < N; i += gridDim.x * 4) {
    int beg = rowp[i], end = rowp[i + 1];
    float a0 = 0.f, a1 = 0.f, a2 = 0.f, a3 = 0.f;
    int e = beg;
    for (; e + 8 <= end; e += 8) {
      int c0 = cols[e], c1 = cols[e + 1], c2 = cols[e + 2], c3 = cols[e + 3];
      int c4 = cols[e + 4], c5 = cols[e + 5], c6 = cols[e + 6], c7 = cols[e + 7];
      float w0 = wv[e], w1 = wv[e + 1], w2 = wv[e + 2], w3 = wv[e + 3];
      float w4 = wv[e + 4], w5 = wv[e + 5], w6 = wv[e + 6], w7 = wv[e + 7];
      if (act) {
        a0 = fmaf(w0, p[(size_t)c0 * CDIM + lane], a0);
        a1 = fmaf(w1, p[(size_t)c1 * CDIM + lane], a1);
        a2 = fmaf(w2, p[(size_t)c2 * CDIM + lane], a2);
        a3 = fmaf(w3, p[(size_t)c3 * CDIM + lane], a3);
        a0 = fmaf(w4, p[(size_t)c4 * CDIM + lane], a0);
        a1 = fmaf(w5, p[(size_t)c5 * CDIM + lane], a1);
        a2 = fmaf(w6, p[(size_t)c6 * CDIM + lane], a2);
        a3 = fmaf(w7, p[(size_t)c7 * CDIM + lane], a3);
      }
    }
    for (; e + 4 <= end; e += 4) {
      int c0 = cols[e], c1 = cols[e + 1], c2 = cols[e + 2], c3 = cols[e + 3];
      float w0 = wv[e], w1 = wv[e + 1], w2 = wv[e + 2], w3 = wv[e + 3];
      if (act) {
        a0 = fmaf(w0, p[(size_t)c0 * CDIM + lane], a0);
        a1 = fmaf(w1, p[(size_t)c1 * CDIM + lane], a1);
        a2 = fmaf(w2, p[(size_t)c2 * CDIM + lane], a2);
        a3 = fmaf(w3, p[(size_t)c3 * CDIM + lane], a3);
      }
    }
    for (; e < end; ++e) {
      int c = cols[e];
      float w = wv[e];
      if (act) a0 = fmaf(w, p[(size_t)c * CDIM + lane], a0);
    }
    if (act) {
      float pvv = p[(size_t)i * CDIM + lane];
      float qvv = fmaf(-0.9f, (a0 + a1) + (a2 + a3), pvv);
      q[(size_t)i * CDIM + lane] = qvv;
      pqacc = fmaf(pvv, qvv, pqacc);
    }
  }
#pragma unroll
  for (int o = 32; o > 0; o >>= 1) pqacc += __shfl_down(pqacc, o);
  __shared__ float wsum[4];
  if (lane == 0) wsum[wid] = pqacc;
  __syncthreads();
  if (threadIdx.x == 0) pqp[blockIdx.x] = (wsum[0] + wsum[1]) + (wsum[2] + wsum[3]);
}

__global__ __launch_bounds__(256) void cg_update(float* __restrict__ x, float* __restrict__ r,
                                                 const float* __restrict__ p,
                                                 const float* __restrict__ q,
                                                 const float* __restrict__ pqp,
                                                 const float* __restrict__ rsold_p,
                                                 float* __restrict__ rsnew_p, int total) {
  __shared__ float red[256];
  float s1 = 0.f, s2 = 0.f;
  for (int i = threadIdx.x; i < RB; i += 256) {
    s1 += pqp[i];
    s2 += rsold_p[i];
  }
  float pq = block_reduce_256(s1, red);
  float rsold = block_reduce_256(s2, red);
  float alpha = (pq > 0.f) ? (rsold / pq) : 0.f;
  float rs = 0.f;
  for (int i = blockIdx.x * 256 + threadIdx.x; i < total; i += gridDim.x * 256) {
    float pvv = p[i], qvv = q[i];
    x[i] = fmaf(alpha, pvv, x[i]);
    float rv2 = fmaf(-alpha, qvv, r[i]);
    r[i] = rv2;
    rs = fmaf(rv2, rv2, rs);
  }
  float bs = block_reduce_256(rs, red);
  if (threadIdx.x == 0) rsnew_p[blockIdx.x] = bs;
}

__global__ __launch_bounds__(256) void cg_axpy(float* __restrict__ p, const float* __restrict__ r,
                                               const float* __restrict__ rsold_p,
                                               const float* __restrict__ rsnew_p, int total) {
  __shared__ float red[256];
  float s1 = 0.f, s2 = 0.f;
  for (int i = threadIdx.x; i < RB; i += 256) {
    s1 += rsold_p[i];
    s2 += rsnew_p[i];
  }
  float rsold = block_reduce_256(s1, red);
  float rsnew = block_reduce_256(s2, red);
  float beta = (rsold > 0.f) ? (rsnew / rsold) : 0.f;
  for (int i = blockIdx.x * 256 + threadIdx.x; i < total; i += gridDim.x * 256) {
    p[i] = fmaf(beta, p[i], r[i]);
  }
}

// ---------------- launch ----------------

extern "C" void kernel_launch(void* const* d_in, const int* in_sizes, int n_in,
                              void* d_out, int out_size, void* d_ws, size_t ws_size,
                              hipStream_t stream) {
  const float* X   = (const float*)d_in[0];
  const int* send  = (const int*)d_in[1];
  const int* recv  = (const int*)d_in[2];
  const float* ew  = (const float*)d_in[3];
  const float* W0  = (const float*)d_in[4];
  const float* b0  = (const float*)d_in[5];
  const float* g0  = (const float*)d_in[6];
  const float* o0  = (const float*)d_in[7];
  const float* W1  = (const float*)d_in[8];
  const float* b1  = (const float*)d_in[9];
  const float* g1  = (const float*)d_in[10];
  const float* o1  = (const float*)d_in[11];
  const float* W2  = (const float*)d_in[12];
  const float* b2  = (const float*)d_in[13];

  const int N = in_sizes[0] / FIN;      // 169343
  const int E2 = in_sizes[1];           // 5418976
  const int total = N * CDIM;

  char* base = (char*)d_ws;
  size_t off = 0;
  auto carve = [&](size_t bytes) -> void* {
    void* ptr = base + off;
    off += (bytes + 255) & ~(size_t)255;
    return ptr;
  };
  int* cnt     = (int*)carve((size_t)N * 4);
  int* rowp    = (int*)carve((size_t)(N + 1) * 4);
  int* cols    = (int*)carve((size_t)E2 * 4);
  float* wv    = (float*)carve((size_t)E2 * 4);
  float* Y     = (float*)carve((size_t)N * HIDN * 4);  // reused for CG vectors
  float* statp = (float*)carve((size_t)SB * 512 * 4);
  float* lnS0  = (float*)carve(256 * 4);
  float* lnT0  = (float*)carve(256 * 4);
  float* lnS1  = (float*)carve(256 * 4);
  float* lnT1  = (float*)carve(256 * 4);
  float* pqp   = (float*)carve((size_t)RB * 4);
  float* rspA  = (float*)carve((size_t)RB * 4);
  float* rspB  = (float*)carve((size_t)RB * 4);
  (void)n_in; (void)out_size;

  // Diagnostic guard: if workspace is too small, do nothing (clean absmax
  // failure instead of an OOB crash).
  if (off > ws_size) return;

  // CG vectors overlay Y (dead after gemm2): 3*total < N*HIDN.
  float* rv = Y;
  float* pv = Y + (size_t)total;
  float* qv = Y + (size_t)2 * total;
  float* xv = (float*)d_out;   // also holds b right after gemm2

  // ---- CSR build (by receiver) ----
  zero_i32<<<RB, 256, 0, stream>>>(cnt, N);
  hist_kernel<<<RB, 256, 0, stream>>>(recv, cnt, E2);
  scan_kernel<<<1, 1024, 0, stream>>>(cnt, rowp, N);
  zero_i32<<<RB, 256, 0, stream>>>(cnt, N);
  scatter_kernel<<<RB, 256, 0, stream>>>(send, recv, ew, rowp, cnt, cols, wv, E2);

  // ---- MLP ----
  const int gm = (N + 127) / 128;
  gemm_kernel<false><<<dim3(gm, HIDN / 64), 256, 0, stream>>>(X, W0, b0, nullptr, nullptr,
                                                              Y, N, FIN, HIDN);
  stats_partial<<<SB, 256, 0, stream>>>(Y, statp, N);
  stats_final<<<HIDN, 256, 0, stream>>>(statp, g0, o0, lnS0, lnT0, N);
  gemm1_inplace<<<gm, 256, 0, stream>>>(Y, W1, b1, lnS0, lnT0, N);
  stats_partial<<<SB, 256, 0, stream>>>(Y, statp, N);
  stats_final<<<HIDN, 256, 0, stream>>>(statp, g1, o1, lnS1, lnT1, N);
  gemm_kernel<true><<<dim3(gm, 1), 256, 0, stream>>>(Y, W2, b2, lnS1, lnT1,
                                                     xv, N, HIDN, CDIM);

  // ---- CG: (I - 0.9 S) x = b, x0 = 0, fixed iteration count ----
  cg_init<<<RB, 256, 0, stream>>>(xv, rv, pv, rspA, total);
  for (int it = 0; it < NITER; ++it) {
    float* rs_old = (it & 1) ? rspB : rspA;
    float* rs_new = (it & 1) ? rspA : rspB;
    cg_matvec<<<RB, 256, 0, stream>>>(pv, qv, rowp, cols, wv, pqp, N);
    cg_update<<<RB, 256, 0, stream>>>(xv, rv, pv, qv, pqp, rs_old, rs_new, total);
    cg_axpy<<<RB, 256, 0, stream>>>(pv, rv, rs_old, rs_new, total);
  }
}

// Round 4
// 5497.515 us; speedup vs baseline: 2.1058x; 1.1624x over previous
//
#include <hip/hip_runtime.h>

#define FIN   128
#define HIDN  256
#define CDIM  40
#define NITER 16
#define RB    2048   // grid for grid-stride CG kernels / partial arrays
#define SB    512    // grid for stats partials

// ---------------- helpers ----------------

__device__ __forceinline__ float block_reduce_256(float v, float* red) {
  const int t = threadIdx.x;
  __syncthreads();           // protect reuse of red across calls
  red[t] = v;
  __syncthreads();
#pragma unroll
  for (int o = 128; o > 0; o >>= 1) {
    if (t < o) red[t] += red[t + o];
    __syncthreads();
  }
  return red[0];             // deterministic sum, visible to all threads
}

// ---------------- CSR build ----------------

__global__ void zero_i32(int* __restrict__ a, int n) {
  int i = blockIdx.x * blockDim.x + threadIdx.x;
  int s = gridDim.x * blockDim.x;
  for (; i < n; i += s) a[i] = 0;
}

__global__ void hist_kernel(const int* __restrict__ recv, int* __restrict__ cnt, int n) {
  int i = blockIdx.x * blockDim.x + threadIdx.x;
  int s = gridDim.x * blockDim.x;
  for (; i < n; i += s) atomicAdd(&cnt[recv[i]], 1);
}

__global__ __launch_bounds__(1024) void scan_kernel(const int* __restrict__ cnt,
                                                    int* __restrict__ rowp, int n) {
  __shared__ int sums[1024];
  const int t = threadIdx.x;
  const int chunk = (n + 1023) >> 10;
  const int lo = t * chunk;
  const int hi = min(lo + chunk, n);
  int s = 0;
  for (int i = lo; i < hi; ++i) s += cnt[i];
  sums[t] = s;
  __syncthreads();
  for (int o = 1; o < 1024; o <<= 1) {
    int v = (t >= o) ? sums[t - o] : 0;
    __syncthreads();
    sums[t] += v;
    __syncthreads();
  }
  int pre = (t == 0) ? 0 : sums[t - 1];
  for (int i = lo; i < hi; ++i) { rowp[i] = pre; pre += cnt[i]; }
  if (t == 0) rowp[n] = sums[1023];
}

__global__ void scatter_kernel(const int* __restrict__ send, const int* __restrict__ recv,
                               const float* __restrict__ ew, const int* __restrict__ rowp,
                               int* __restrict__ cur, int* __restrict__ cols,
                               float* __restrict__ wv, int n) {
  int i = blockIdx.x * blockDim.x + threadIdx.x;
  int s = gridDim.x * blockDim.x;
  for (; i < n; i += s) {
    int node = recv[i];
    int pos = atomicAdd(&cur[node], 1);
    int slot = rowp[node] + pos;
    cols[slot] = send[i];
    wv[slot] = ew[i];
  }
}

// ---------------- GEMM (f32, 128x64 tile, 8x4 per thread, BK=32) ----------
// C[M,Nn] = act(A)[M,K] @ W[K,Nn] + bias. If LNA: a' = relu(a*lnS[k]+lnT[k]).
// K must be a multiple of 32.

template <bool LNA>
__global__ __launch_bounds__(256) void gemm_kernel(
    const float* __restrict__ A, const float* __restrict__ W,
    const float* __restrict__ bias, const float* __restrict__ lnS,
    const float* __restrict__ lnT, float* __restrict__ C, int M, int K, int Nn) {
  __shared__ float As[32][136];
  __shared__ float Bs[32][64];
  __shared__ float sS[256];
  __shared__ float sT[256];
  const int tid = threadIdx.x;
  if (LNA) {
    if (tid < K) { sS[tid] = lnS[tid]; sT[tid] = lnT[tid]; }
  }
  const int tx = tid & 15, ty = tid >> 4;
  const int arow = tid >> 1, acol = (tid & 1) * 16;   // 16 k-floats per thread
  const int brow = tid >> 3, bcol = (tid & 7) * 8;    // 8 n-floats per thread
  const int rowBase = blockIdx.x * 128;
  const int colBase = blockIdx.y * 64;
  const int gr = rowBase + arow;
  float acc[8][4] = {};
  for (int k0 = 0; k0 < K; k0 += 32) {
    float av[16];
    if (gr < M) {
      const float4* ap = reinterpret_cast<const float4*>(A + (size_t)gr * K + k0 + acol);
#pragma unroll
      for (int v4 = 0; v4 < 4; ++v4) {
        float4 vv = ap[v4];
        av[v4 * 4 + 0] = vv.x; av[v4 * 4 + 1] = vv.y;
        av[v4 * 4 + 2] = vv.z; av[v4 * 4 + 3] = vv.w;
      }
    } else {
#pragma unroll
      for (int j = 0; j < 16; ++j) av[j] = 0.f;
    }
    float bv[8];
    const int gk = k0 + brow;
#pragma unroll
    for (int j = 0; j < 8; ++j) {
      int gc = colBase + bcol + j;
      bv[j] = (gc < Nn) ? W[(size_t)gk * Nn + gc] : 0.f;
    }
    __syncthreads();   // k0=0: orders sS/sT writes; else: protects As/Bs readers
    if (LNA) {
#pragma unroll
      for (int j = 0; j < 16; ++j) {
        int k = k0 + acol + j;
        av[j] = fmaxf(fmaf(av[j], sS[k], sT[k]), 0.f);
      }
    }
#pragma unroll
    for (int j = 0; j < 16; ++j) As[acol + j][arow] = av[j];
#pragma unroll
    for (int j = 0; j < 8; ++j) Bs[brow][bcol + j] = bv[j];
    __syncthreads();
#pragma unroll
    for (int kk = 0; kk < 32; ++kk) {
      float a[8], b[4];
#pragma unroll
      for (int i2 = 0; i2 < 8; ++i2) a[i2] = As[kk][ty * 8 + i2];
#pragma unroll
      for (int j = 0; j < 4; ++j) b[j] = Bs[kk][tx * 4 + j];
#pragma unroll
      for (int i2 = 0; i2 < 8; ++i2)
#pragma unroll
        for (int j = 0; j < 4; ++j)
          acc[i2][j] = fmaf(a[i2], b[j], acc[i2][j]);
    }
  }
#pragma unroll
  for (int i2 = 0; i2 < 8; ++i2) {
    int orow = rowBase + ty * 8 + i2;
    if (orow >= M) continue;
#pragma unroll
    for (int j = 0; j < 4; ++j) {
      int ocol = colBase + tx * 4 + j;
      if (ocol < Nn) C[(size_t)orow * Nn + ocol] = acc[i2][j] + bias[ocol];
    }
  }
}

// ---------------- in-place layer-1 GEMM ----------------
// Y <- relu(Y*lnS + lnT) @ W1 + b1. 128 rows/block, K staged in two
// 128-wide halves (LDS ~78 KB -> 2 blocks/CU), Bs in 32-k chunks.

__global__ __launch_bounds__(256, 2) void gemm1_inplace(
    float* __restrict__ Y, const float* __restrict__ W,
    const float* __restrict__ bias, const float* __restrict__ lnS,
    const float* __restrict__ lnT, int M) {
  __shared__ float As[128][132];   // [k-within-half][row]
  __shared__ float Bs[32][64];
  __shared__ float sS[HIDN];
  __shared__ float sT[HIDN];
  const int tid = threadIdx.x;
  sS[tid] = lnS[tid];
  sT[tid] = lnT[tid];
  __syncthreads();                 // sS/sT ready for the As transform
  const int rowBase = blockIdx.x * 128;
  const int r = tid >> 1;            // 0..127
  const int c0 = (tid & 1) * 64;     // 0 or 64 within the 128-wide half
  const int gr = rowBase + r;
  const int tx = tid & 15, ty = tid >> 4;
  const int brow = tid >> 3, bcol = (tid & 7) * 8;
  float acc[4][8][4] = {};
#pragma unroll
  for (int kh = 0; kh < 2; ++kh) {
    if (kh == 1) __syncthreads();  // protect As from previous compute readers
    if (gr < M) {
      const float4* src =
          reinterpret_cast<const float4*>(Y + (size_t)gr * HIDN + kh * 128 + c0);
#pragma unroll
      for (int v4 = 0; v4 < 16; ++v4) {
        float4 vv = src[v4];
        int cl = c0 + v4 * 4;
        int cg = kh * 128 + cl;
        As[cl + 0][r] = fmaxf(fmaf(vv.x, sS[cg + 0], sT[cg + 0]), 0.f);
        As[cl + 1][r] = fmaxf(fmaf(vv.y, sS[cg + 1], sT[cg + 1]), 0.f);
        As[cl + 2][r] = fmaxf(fmaf(vv.z, sS[cg + 2], sT[cg + 2]), 0.f);
        As[cl + 3][r] = fmaxf(fmaf(vv.w, sS[cg + 3], sT[cg + 3]), 0.f);
      }
    } else {
#pragma unroll
      for (int v4 = 0; v4 < 16; ++v4) {
        int cl = c0 + v4 * 4;
        As[cl + 0][r] = 0.f; As[cl + 1][r] = 0.f;
        As[cl + 2][r] = 0.f; As[cl + 3][r] = 0.f;
      }
    }
#pragma unroll
    for (int ct = 0; ct < 4; ++ct) {
      const int colBase = ct * 64;
      for (int k0 = 0; k0 < 128; k0 += 32) {
        float bv[8];
        const float4* wp = reinterpret_cast<const float4*>(
            W + (size_t)(kh * 128 + k0 + brow) * HIDN + colBase + bcol);
        float4 w0 = wp[0], w1 = wp[1];
        bv[0] = w0.x; bv[1] = w0.y; bv[2] = w0.z; bv[3] = w0.w;
        bv[4] = w1.x; bv[5] = w1.y; bv[6] = w1.z; bv[7] = w1.w;
        __syncthreads();   // first pass also orders the As writes above
#pragma unroll
        for (int j = 0; j < 8; ++j) Bs[brow][bcol + j] = bv[j];
        __syncthreads();
#pragma unroll
        for (int kk = 0; kk < 32; ++kk) {
          float a[8], b[4];
#pragma unroll
          for (int i2 = 0; i2 < 8; ++i2) a[i2] = As[k0 + kk][ty * 8 + i2];
#pragma unroll
          for (int j = 0; j < 4; ++j) b[j] = Bs[kk][tx * 4 + j];
#pragma unroll
          for (int i2 = 0; i2 < 8; ++i2)
#pragma unroll
            for (int j = 0; j < 4; ++j)
              acc[ct][i2][j] = fmaf(a[i2], b[j], acc[ct][i2][j]);
        }
      }
    }
  }
#pragma unroll
  for (int ct = 0; ct < 4; ++ct) {
#pragma unroll
    for (int i2 = 0; i2 < 8; ++i2) {
      int orow = rowBase + ty * 8 + i2;
      if (orow >= M) continue;
#pragma unroll
      for (int j = 0; j < 4; ++j) {
        int oc = ct * 64 + tx * 4 + j;
        Y[(size_t)orow * HIDN + oc] = acc[ct][i2][j] + bias[oc];
      }
    }
  }
}

// ---------------- LayerNorm(axis=0) stats ----------------

__global__ __launch_bounds__(256) void stats_partial(const float* __restrict__ Y,
                                                     float* __restrict__ part, int M) {
  const int t = threadIdx.x;   // column
  float s = 0.f, s2 = 0.f;
  for (int row = blockIdx.x; row < M; row += SB) {
    float v = Y[(size_t)row * HIDN + t];
    s += v;
    s2 = fmaf(v, v, s2);
  }
  part[(size_t)blockIdx.x * 512 + t] = s;
  part[(size_t)blockIdx.x * 512 + 256 + t] = s2;
}

__global__ __launch_bounds__(256) void stats_final(const float* __restrict__ part,
                                                   const float* __restrict__ g,
                                                   const float* __restrict__ o,
                                                   float* __restrict__ lnS,
                                                   float* __restrict__ lnT, int M) {
  __shared__ float red[256];
  const int col = blockIdx.x;
  float s = 0.f, s2 = 0.f;
  for (int b = threadIdx.x; b < SB; b += 256) {
    s += part[(size_t)b * 512 + col];
    s2 += part[(size_t)b * 512 + 256 + col];
  }
  float ts = block_reduce_256(s, red);
  float ts2 = block_reduce_256(s2, red);
  if (threadIdx.x == 0) {
    float invM = 1.f / (float)M;
    float mean = ts * invM;
    float var = fmaxf(ts2 * invM - mean * mean, 0.f);
    float rstd = rsqrtf(var + 1e-5f);
    float sc = g[col] * rstd;
    lnS[col] = sc;
    lnT[col] = o[col] - mean * sc;
  }
}

// ---------------- CG ----------------
// b aliases x (both d_out): read b first, then zero x — same thread, safe.
// All vector kernels use float4 (total is a multiple of 4).

__global__ __launch_bounds__(256) void cg_init(float4* __restrict__ bx,
                                               float4* __restrict__ r,
                                               float4* __restrict__ p,
                                               float* __restrict__ rs_p, int total4) {
  __shared__ float red[256];
  float rs = 0.f;
  for (int i = blockIdx.x * 256 + threadIdx.x; i < total4; i += gridDim.x * 256) {
    float4 v = bx[i];
    r[i] = v;
    p[i] = v;
    bx[i] = make_float4(0.f, 0.f, 0.f, 0.f);   // x = 0
    rs = fmaf(v.x, v.x, fmaf(v.y, v.y, fmaf(v.z, v.z, fmaf(v.w, v.w, rs))));
  }
  float s = block_reduce_256(rs, red);
  if (threadIdx.x == 0) rs_p[blockIdx.x] = s;
}

// q = (I - 0.9 S) p ; per-block partial of dot(p,q). One wave per node,
// 8-deep edge unroll for gather-latency hiding.
__global__ __launch_bounds__(256) void cg_matvec(const float* __restrict__ p,
                                                 float* __restrict__ q,
                                                 const int* __restrict__ rowp,
                                                 const int* __restrict__ cols,
                                                 const float* __restrict__ wv,
                                                 float* __restrict__ pqp, int N) {
  const int lane = threadIdx.x & 63;
  const int wid = threadIdx.x >> 6;
  const bool act = lane < CDIM;
  float pqacc = 0.f;
  for (int i = blockIdx.x * 4 + wid; i < N; i += gridDim.x * 4) {
    int beg = rowp[i], end = rowp[i + 1];
    float a0 = 0.f, a1 = 0.f, a2 = 0.f, a3 = 0.f;
    int e = beg;
    for (; e + 8 <= end; e += 8) {
      int c0 = cols[e], c1 = cols[e + 1], c2 = cols[e + 2], c3 = cols[e + 3];
      int c4 = cols[e + 4], c5 = cols[e + 5], c6 = cols[e + 6], c7 = cols[e + 7];
      float w0 = wv[e], w1 = wv[e + 1], w2 = wv[e + 2], w3 = wv[e + 3];
      float w4 = wv[e + 4], w5 = wv[e + 5], w6 = wv[e + 6], w7 = wv[e + 7];
      if (act) {
        a0 = fmaf(w0, p[(size_t)c0 * CDIM + lane], a0);
        a1 = fmaf(w1, p[(size_t)c1 * CDIM + lane], a1);
        a2 = fmaf(w2, p[(size_t)c2 * CDIM + lane], a2);
        a3 = fmaf(w3, p[(size_t)c3 * CDIM + lane], a3);
        a0 = fmaf(w4, p[(size_t)c4 * CDIM + lane], a0);
        a1 = fmaf(w5, p[(size_t)c5 * CDIM + lane], a1);
        a2 = fmaf(w6, p[(size_t)c6 * CDIM + lane], a2);
        a3 = fmaf(w7, p[(size_t)c7 * CDIM + lane], a3);
      }
    }
    for (; e + 4 <= end; e += 4) {
      int c0 = cols[e], c1 = cols[e + 1], c2 = cols[e + 2], c3 = cols[e + 3];
      float w0 = wv[e], w1 = wv[e + 1], w2 = wv[e + 2], w3 = wv[e + 3];
      if (act) {
        a0 = fmaf(w0, p[(size_t)c0 * CDIM + lane], a0);
        a1 = fmaf(w1, p[(size_t)c1 * CDIM + lane], a1);
        a2 = fmaf(w2, p[(size_t)c2 * CDIM + lane], a2);
        a3 = fmaf(w3, p[(size_t)c3 * CDIM + lane], a3);
      }
    }
    for (; e < end; ++e) {
      int c = cols[e];
      float w = wv[e];
      if (act) a0 = fmaf(w, p[(size_t)c * CDIM + lane], a0);
    }
    if (act) {
      float pvv = p[(size_t)i * CDIM + lane];
      float qvv = fmaf(-0.9f, (a0 + a1) + (a2 + a3), pvv);
      q[(size_t)i * CDIM + lane] = qvv;
      pqacc = fmaf(pvv, qvv, pqacc);
    }
  }
#pragma unroll
  for (int o = 32; o > 0; o >>= 1) pqacc += __shfl_down(pqacc, o);
  __shared__ float wsum[4];
  if (lane == 0) wsum[wid] = pqacc;
  __syncthreads();
  if (threadIdx.x == 0) pqp[blockIdx.x] = (wsum[0] + wsum[1]) + (wsum[2] + wsum[3]);
}

__global__ __launch_bounds__(256) void cg_update(float4* __restrict__ x,
                                                 float4* __restrict__ r,
                                                 const float4* __restrict__ p,
                                                 const float4* __restrict__ q,
                                                 const float* __restrict__ pqp,
                                                 const float* __restrict__ rsold_p,
                                                 float* __restrict__ rsnew_p, int total4) {
  __shared__ float red[256];
  float s1 = 0.f, s2 = 0.f;
  for (int i = threadIdx.x; i < RB; i += 256) {
    s1 += pqp[i];
    s2 += rsold_p[i];
  }
  float pq = block_reduce_256(s1, red);
  float rsold = block_reduce_256(s2, red);
  float alpha = (pq > 0.f) ? (rsold / pq) : 0.f;
  float rs = 0.f;
  for (int i = blockIdx.x * 256 + threadIdx.x; i < total4; i += gridDim.x * 256) {
    float4 pv4 = p[i], qv4 = q[i], xv4 = x[i], rv4 = r[i];
    xv4.x = fmaf(alpha, pv4.x, xv4.x);
    xv4.y = fmaf(alpha, pv4.y, xv4.y);
    xv4.z = fmaf(alpha, pv4.z, xv4.z);
    xv4.w = fmaf(alpha, pv4.w, xv4.w);
    rv4.x = fmaf(-alpha, qv4.x, rv4.x);
    rv4.y = fmaf(-alpha, qv4.y, rv4.y);
    rv4.z = fmaf(-alpha, qv4.z, rv4.z);
    rv4.w = fmaf(-alpha, qv4.w, rv4.w);
    x[i] = xv4;
    r[i] = rv4;
    rs = fmaf(rv4.x, rv4.x, fmaf(rv4.y, rv4.y, fmaf(rv4.z, rv4.z, fmaf(rv4.w, rv4.w, rs))));
  }
  float bs = block_reduce_256(rs, red);
  if (threadIdx.x == 0) rsnew_p[blockIdx.x] = bs;
}

__global__ __launch_bounds__(256) void cg_axpy(float4* __restrict__ p,
                                               const float4* __restrict__ r,
                                               const float* __restrict__ rsold_p,
                                               const float* __restrict__ rsnew_p, int total4) {
  __shared__ float red[256];
  float s1 = 0.f, s2 = 0.f;
  for (int i = threadIdx.x; i < RB; i += 256) {
    s1 += rsold_p[i];
    s2 += rsnew_p[i];
  }
  float rsold = block_reduce_256(s1, red);
  float rsnew = block_reduce_256(s2, red);
  float beta = (rsold > 0.f) ? (rsnew / rsold) : 0.f;
  for (int i = blockIdx.x * 256 + threadIdx.x; i < total4; i += gridDim.x * 256) {
    float4 pv4 = p[i], rv4 = r[i];
    pv4.x = fmaf(beta, pv4.x, rv4.x);
    pv4.y = fmaf(beta, pv4.y, rv4.y);
    pv4.z = fmaf(beta, pv4.z, rv4.z);
    pv4.w = fmaf(beta, pv4.w, rv4.w);
    p[i] = pv4;
  }
}

// ---------------- launch ----------------

extern "C" void kernel_launch(void* const* d_in, const int* in_sizes, int n_in,
                              void* d_out, int out_size, void* d_ws, size_t ws_size,
                              hipStream_t stream) {
  const float* X   = (const float*)d_in[0];
  const int* send  = (const int*)d_in[1];
  const int* recv  = (const int*)d_in[2];
  const float* ew  = (const float*)d_in[3];
  const float* W0  = (const float*)d_in[4];
  const float* b0  = (const float*)d_in[5];
  const float* g0  = (const float*)d_in[6];
  const float* o0  = (const float*)d_in[7];
  const float* W1  = (const float*)d_in[8];
  const float* b1  = (const float*)d_in[9];
  const float* g1  = (const float*)d_in[10];
  const float* o1  = (const float*)d_in[11];
  const float* W2  = (const float*)d_in[12];
  const float* b2  = (const float*)d_in[13];

  const int N = in_sizes[0] / FIN;      // 169343
  const int E2 = in_sizes[1];           // 5418976
  const int total = N * CDIM;
  const int total4 = total / 4;

  char* base = (char*)d_ws;
  size_t off = 0;
  auto carve = [&](size_t bytes) -> void* {
    void* ptr = base + off;
    off += (bytes + 255) & ~(size_t)255;
    return ptr;
  };
  int* cnt     = (int*)carve((size_t)N * 4);
  int* rowp    = (int*)carve((size_t)(N + 1) * 4);
  int* cols    = (int*)carve((size_t)E2 * 4);
  float* wv    = (float*)carve((size_t)E2 * 4);
  float* Y     = (float*)carve((size_t)N * HIDN * 4);  // reused for CG vectors
  float* statp = (float*)carve((size_t)SB * 512 * 4);
  float* lnS0  = (float*)carve(256 * 4);
  float* lnT0  = (float*)carve(256 * 4);
  float* lnS1  = (float*)carve(256 * 4);
  float* lnT1  = (float*)carve(256 * 4);
  float* pqp   = (float*)carve((size_t)RB * 4);
  float* rspA  = (float*)carve((size_t)RB * 4);
  float* rspB  = (float*)carve((size_t)RB * 4);
  (void)n_in; (void)out_size;

  // Diagnostic guard: if workspace is too small, do nothing (clean absmax
  // failure instead of an OOB crash).
  if (off > ws_size) return;

  // CG vectors overlay Y (dead after gemm2): 3*total < N*HIDN.
  float* rv = Y;
  float* pv = Y + (size_t)total;
  float* qv = Y + (size_t)2 * total;
  float* xv = (float*)d_out;   // also holds b right after gemm2

  // ---- CSR build (by receiver) ----
  zero_i32<<<RB, 256, 0, stream>>>(cnt, N);
  hist_kernel<<<RB, 256, 0, stream>>>(recv, cnt, E2);
  scan_kernel<<<1, 1024, 0, stream>>>(cnt, rowp, N);
  zero_i32<<<RB, 256, 0, stream>>>(cnt, N);
  scatter_kernel<<<RB, 256, 0, stream>>>(send, recv, ew, rowp, cnt, cols, wv, E2);

  // ---- MLP ----
  const int gm = (N + 127) / 128;
  gemm_kernel<false><<<dim3(gm, HIDN / 64), 256, 0, stream>>>(X, W0, b0, nullptr, nullptr,
                                                              Y, N, FIN, HIDN);
  stats_partial<<<SB, 256, 0, stream>>>(Y, statp, N);
  stats_final<<<HIDN, 256, 0, stream>>>(statp, g0, o0, lnS0, lnT0, N);
  gemm1_inplace<<<gm, 256, 0, stream>>>(Y, W1, b1, lnS0, lnT0, N);
  stats_partial<<<SB, 256, 0, stream>>>(Y, statp, N);
  stats_final<<<HIDN, 256, 0, stream>>>(statp, g1, o1, lnS1, lnT1, N);
  gemm_kernel<true><<<dim3(gm, 1), 256, 0, stream>>>(Y, W2, b2, lnS1, lnT1,
                                                     xv, N, HIDN, CDIM);

  // ---- CG: (I - 0.9 S) x = b, x0 = 0, fixed iteration count ----
  cg_init<<<RB, 256, 0, stream>>>((float4*)xv, (float4*)rv, (float4*)pv, rspA, total4);
  for (int it = 0; it < NITER; ++it) {
    float* rs_old = (it & 1) ? rspB : rspA;
    float* rs_new = (it & 1) ? rspA : rspB;
    cg_matvec<<<RB, 256, 0, stream>>>(pv, qv, rowp, cols, wv, pqp, N);
    cg_update<<<RB, 256, 0, stream>>>((float4*)xv, (float4*)rv, (const float4*)pv,
                                      (const float4*)qv, pqp, rs_old, rs_new, total4);
    cg_axpy<<<RB, 256, 0, stream>>>((float4*)pv, (const float4*)rv, rs_old, rs_new, total4);
  }
}